// Round 4
// baseline (4039.182 us; speedup 1.0000x reference)
//
#include <hip/hip_runtime.h>

#define N_ROWS 65536
#define DIM    512
#define K_CENT 4096
#define TILE_M 128
#define TILE_N 256
#define BK     32
#define KSTEPS (DIM / BK)        // 16
#define NKT    (K_CENT / TILE_N) // 16 total kt tiles
#define NKT_SPLIT 8              // kt tiles per block in split mode
#define THREADS 512
#define MARGIN 6.0f
#define CAND_CAP 1536
#define COMPACT_TRIG 1024

typedef _Float16 half8 __attribute__((ext_vector_type(8)));
typedef float floatx4 __attribute__((ext_vector_type(4)));

// order-preserving float<->uint map
__device__ __forceinline__ unsigned mapF(float f) {
  unsigned u = __float_as_uint(f);
  return (u & 0x80000000u) ? ~u : (u | 0x80000000u);
}
__device__ __forceinline__ float unmapF(unsigned m) {
  unsigned u = (m & 0x80000000u) ? (m ^ 0x80000000u) : ~m;
  return __uint_as_float(u);
}

__device__ __forceinline__ void gload_lds16(const void* g, void* l) {
  __builtin_amdgcn_global_load_lds(
      (const __attribute__((address_space(1))) void*)g,
      (__attribute__((address_space(3))) void*)l, 16, 0, 0);
}

// fp32 -> fp16 conversion for x and center; csq (||c_fp16||^2) fused into the
// center branch (each 64-lane wave covers exactly one 512-dim center row).
__global__ void prep_convert(const float* __restrict__ x, const float* __restrict__ c,
                             _Float16* __restrict__ xh, _Float16* __restrict__ ch,
                             float* __restrict__ csqg) {
  const size_t nx = (size_t)N_ROWS * DIM;
  size_t i = ((size_t)blockIdx.x * blockDim.x + threadIdx.x) * 8;
  if (i < nx) {
    floatx4 a = *(const floatx4*)(x + i);
    floatx4 b = *(const floatx4*)(x + i + 4);
    half8 h;
#pragma unroll
    for (int e = 0; e < 4; ++e) { h[e] = (_Float16)a[e]; h[4 + e] = (_Float16)b[e]; }
    *(half8*)(xh + i) = h;
  } else if (i < nx + (size_t)K_CENT * DIM) {
    size_t off = i - nx;
    floatx4 a = *(const floatx4*)(c + off);
    floatx4 b = *(const floatx4*)(c + off + 4);
    half8 h;
    float s = 0.f;
#pragma unroll
    for (int e = 0; e < 4; ++e) { h[e] = (_Float16)a[e]; h[4 + e] = (_Float16)b[e]; }
#pragma unroll
    for (int e = 0; e < 8; ++e) { float v = (float)h[e]; s += v * v; }
    *(half8*)(ch + off) = h;
#pragma unroll
    for (int o = 1; o < 64; o <<= 1) s += __shfl_xor(s, o, 64);
    if ((threadIdx.x & 63) == 0) csqg[off >> 9] = s;
  }
}

__global__ void finalize_out(const unsigned long long* __restrict__ gbest,
                             int* __restrict__ out) {
  int i = blockIdx.x * blockDim.x + threadIdx.x;
  out[i] = (int)(gbest[i] & 0xFFFull);
}

// MODE 0: no ws fallback (fp32 loads, on-the-fly convert, LDS csq, all 16 kt,
//         local best, direct out write, grid 512)
// MODE 2: fp16+csq pre-computed in ws, SPLIT-K over centers: grid 1024,
//         block b handles rows (b&511) and kt range ((b>>9)*8 .. +8);
//         results merged via global fp64-packed-key atomicMin in ws.
//
// 512 threads = 8 waves (2 wave-rows x 4 wave-cols), block tile 128x256,
// wave tile 64x64 (16 MFMA / ks / wave), 16x16x32 f16 MFMA, BK=32.
// Single pass over assigned kt: tighten per-row running min first (shfl
// pre-reduced), then collect candidates vs runmin+MARGIN (prefix superset),
// fp64-exact refine of survivors.
// XOR chunk swizzle ((row>>1)&3) keeps ds_read_b128 conflict-free while
// staying compatible with global_load_lds lane-contiguous dst.
template <int MODE>
__global__ __launch_bounds__(THREADS, 8)
void kmeans_argmin(const float* __restrict__ x, const float* __restrict__ cent,
                   const _Float16* __restrict__ xh, const _Float16* __restrict__ ch,
                   const float* __restrict__ csqg, unsigned long long* __restrict__ gbest,
                   int* __restrict__ out) {
  __shared__ _Float16 ldsA[TILE_M * BK];        // 8 KB
  __shared__ _Float16 ldsB[TILE_N * BK];        // 16 KB
  __shared__ float csq4[TILE_N][4];             // MODE 0 only (eliminated in MODE 2)
  __shared__ unsigned sminU[TILE_M];
  __shared__ unsigned long long best[TILE_M];   // MODE 0 only
  __shared__ unsigned candKey[CAND_CAP];        // 6 KB
  __shared__ float candS[CAND_CAP];             // 6 KB
  __shared__ int candCount;

  char* ldsAc = (char*)ldsA;
  char* ldsBc = (char*)ldsB;

  const int t = threadIdx.x;
  const int lane = t & 63;
  const int wave = t >> 6;   // 0..7
  const int wm = wave >> 2;  // 0..1 row-waves
  const int wn = wave & 3;   // 0..3 col-waves
  const int quad = lane >> 4;
  const int l15 = lane & 15;
  const int rowBlock = (MODE == 2) ? (blockIdx.x & 511) * TILE_M : blockIdx.x * TILE_M;
  const int ktStart = (MODE == 2) ? (int)(blockIdx.x >> 9) * NKT_SPLIT : 0;
  const int ktEnd = ktStart + ((MODE == 2) ? NKT_SPLIT : NKT);

  if (t < TILE_M) { sminU[t] = 0xFFFFFFFFu; if (MODE == 0) best[t] = ~0ull; }
  if (t == 0) candCount = 0;

  // staging: thread t owns A slot t; B slots t and t+512. swizzled source chunk.
  const int srA = t >> 2;
  const int sckA = (t & 3) ^ ((srA >> 1) & 3);
  const int srB1 = (t + 512) >> 2;
  const int sckB0 = (t & 3) ^ ((srA >> 1) & 3);
  const int sckB1 = (t & 3) ^ ((srB1 >> 1) & 3);

  for (int kt = ktStart; kt < ktEnd; ++kt) {
    const int ktBase = kt * TILE_N;
    if (MODE == 0) { ((float*)csq4)[t] = 0.f; ((float*)csq4)[t + 512] = 0.f; }
    floatx4 acc[4][4];
#pragma unroll
    for (int fm = 0; fm < 4; ++fm)
#pragma unroll
      for (int fn = 0; fn < 4; ++fn) acc[fm][fn] = (floatx4){0.f, 0.f, 0.f, 0.f};

    for (int ks = 0; ks < KSTEPS; ++ks) {
      const int kd = ks * BK;
      if (MODE == 2) {
        gload_lds16(xh + (size_t)(rowBlock + srA) * DIM + kd + sckA * 8,
                    ldsAc + (size_t)wave * 1024);
        gload_lds16(ch + (size_t)(ktBase + srA) * DIM + kd + sckB0 * 8,
                    ldsBc + (size_t)wave * 1024);
        gload_lds16(ch + (size_t)(ktBase + srB1) * DIM + kd + sckB1 * 8,
                    ldsBc + 8192 + (size_t)wave * 1024);
      } else {
        const float* gA = x + (size_t)(rowBlock + srA) * DIM + kd + sckA * 8;
        floatx4 a0 = *(const floatx4*)gA, a1 = *(const floatx4*)(gA + 4);
        half8 ha;
#pragma unroll
        for (int e = 0; e < 4; ++e) { ha[e] = (_Float16)a0[e]; ha[4 + e] = (_Float16)a1[e]; }
        *(half8*)(ldsAc + (size_t)t * 16) = ha;
#pragma unroll
        for (int p = 0; p < 2; ++p) {
          int sr = p ? srB1 : srA;
          int sck = p ? sckB1 : sckB0;
          int slot = p * 512 + t;
          const float* gB = cent + (size_t)(ktBase + sr) * DIM + kd + sck * 8;
          floatx4 b0 = *(const floatx4*)gB, b1 = *(const floatx4*)(gB + 4);
          half8 hb;
          float s = 0.f;
#pragma unroll
          for (int e = 0; e < 4; ++e) { hb[e] = (_Float16)b0[e]; hb[4 + e] = (_Float16)b1[e]; }
#pragma unroll
          for (int e = 0; e < 8; ++e) { float v = (float)hb[e]; s += v * v; }
          *(half8*)(ldsBc + (size_t)slot * 16) = hb;
          csq4[sr][slot & 3] += s;
        }
      }
      __syncthreads();

      half8 af[4], bf[4];
#pragma unroll
      for (int fm = 0; fm < 4; ++fm) {
        int row = wm * 64 + fm * 16 + l15;
        int slot = (row << 2) | (quad ^ ((row >> 1) & 3));
        af[fm] = *(const half8*)(ldsAc + slot * 16);
      }
#pragma unroll
      for (int fn = 0; fn < 4; ++fn) {
        int cl = wn * 64 + fn * 16 + l15;
        int slot = (cl << 2) | (quad ^ ((cl >> 1) & 3));
        bf[fn] = *(const half8*)(ldsBc + slot * 16);
      }
#pragma unroll
      for (int fm = 0; fm < 4; ++fm)
#pragma unroll
        for (int fn = 0; fn < 4; ++fn)
          acc[fm][fn] = __builtin_amdgcn_mfma_f32_16x16x32_f16(af[fm], bf[fn], acc[fm][fn], 0, 0, 0);
      __syncthreads();
    }

    // ---- epilogue: s = ||c||^2 - 2*cross (||x||^2 constant per row, dropped)
    // C layout 16x16: col = lane&15, row = quad*4 + e  [m89-verified]
    float cs[4];
#pragma unroll
    for (int fn = 0; fn < 4; ++fn) {
      int cl = wn * 64 + fn * 16 + l15;
      cs[fn] = (MODE == 2) ? csqg[ktBase + cl]
                           : (csq4[cl][0] + csq4[cl][1] + csq4[cl][2] + csq4[cl][3]);
    }

    // tighten running min FIRST (shfl pre-reduce over the 16 lanes sharing rows)
#pragma unroll
    for (int fm = 0; fm < 4; ++fm)
#pragma unroll
      for (int e = 0; e < 4; ++e) {
        float v = 3.4e38f;
#pragma unroll
        for (int fn = 0; fn < 4; ++fn)
          v = fminf(v, cs[fn] - 2.f * acc[fm][fn][e]);
        v = fminf(v, __shfl_xor(v, 1, 64));
        v = fminf(v, __shfl_xor(v, 2, 64));
        v = fminf(v, __shfl_xor(v, 4, 64));
        v = fminf(v, __shfl_xor(v, 8, 64));
        if (l15 == 0)
          atomicMin(&sminU[wm * 64 + fm * 16 + quad * 4 + e], mapF(v));
      }
    __syncthreads();

    float thrR[4][4];
#pragma unroll
    for (int fm = 0; fm < 4; ++fm)
#pragma unroll
      for (int e = 0; e < 4; ++e)
        thrR[fm][e] = unmapF(sminU[wm * 64 + fm * 16 + quad * 4 + e]) + MARGIN;

    // collect against the tightened (still prefix, hence superset) threshold
#pragma unroll
    for (int fn = 0; fn < 4; ++fn) {
      int k = ktBase + wn * 64 + fn * 16 + l15;
#pragma unroll
      for (int fm = 0; fm < 4; ++fm)
#pragma unroll
        for (int e = 0; e < 4; ++e) {
          float s = cs[fn] - 2.f * acc[fm][fn][e];
          if (s <= thrR[fm][e]) {
            int idx = atomicAdd(&candCount, 1);
            if (idx < CAND_CAP) {
              candKey[idx] = ((unsigned)k << 7) | (unsigned)(wm * 64 + fm * 16 + quad * 4 + e);
              candS[idx] = s;
            }
          }
        }
    }
    __syncthreads();

    // compaction backstop against tightened threshold (rarely triggers)
    if (candCount > COMPACT_TRIG) {
      int cc = candCount; if (cc > CAND_CAP) cc = CAND_CAP;
      unsigned myK[4]; float myS[4]; int myN = 0;
      for (int i = t; i < cc; i += THREADS) {
        int rl = candKey[i] & 127;
        if (candS[i] <= unmapF(sminU[rl]) + MARGIN) {
          myK[myN] = candKey[i]; myS[myN] = candS[i]; ++myN;
        }
      }
      __syncthreads();
      if (t == 0) candCount = 0;
      __syncthreads();
      int base = atomicAdd(&candCount, myN);
      for (int j = 0; j < myN; ++j) { candKey[base + j] = myK[j]; candS[base + j] = myS[j]; }
      __syncthreads();
    }
  }

  // ---- fp64-exact refinement of surviving candidates (original fp32 inputs)
  int cnt = candCount; if (cnt > CAND_CAP) cnt = CAND_CAP;
  const int g = t >> 4;   // 32 groups of 16 lanes
  const int sl = t & 15;
  for (int ci = g; ci < cnt; ci += 32) {
    unsigned cd = candKey[ci];
    int rl = cd & 127;
    if (candS[ci] > unmapF(sminU[rl]) + MARGIN) continue;  // group-uniform branch
    int k = cd >> 7;
    const float* xr = x + (size_t)(rowBlock + rl) * DIM;
    const float* cr = cent + (size_t)k * DIM;
    double d = 0.0;
#pragma unroll
    for (int j = 0; j < DIM / 64; ++j) {
      floatx4 xv = *(const floatx4*)(xr + j * 64 + sl * 4);
      floatx4 cv = *(const floatx4*)(cr + j * 64 + sl * 4);
#pragma unroll
      for (int e = 0; e < 4; ++e) {
        double df = (double)xv[e] - (double)cv[e];
        d += df * df;
      }
    }
#pragma unroll
    for (int off = 1; off < 16; off <<= 1) d += __shfl_xor(d, off, 64);
    if (sl == 0) {
      // positive doubles order as uint64; low 12 mantissa bits -> index (ties: lower k)
      unsigned long long key =
          ((unsigned long long)__double_as_longlong(d) & ~0xFFFull) | (unsigned long long)k;
      if (MODE == 2) atomicMin(&gbest[rowBlock + rl], key);
      else           atomicMin(&best[rl], key);
    }
  }
  if (MODE == 0) {
    __syncthreads();
    if (t < TILE_M) out[rowBlock + t] = (int)(best[t] & 0xFFFull);
  }
}

extern "C" void kernel_launch(void* const* d_in, const int* in_sizes, int n_in,
                              void* d_out, int out_size, void* d_ws, size_t ws_size,
                              hipStream_t stream) {
  const float* x = (const float*)d_in[0];
  const float* cent = (const float*)d_in[1];
  int* out = (int*)d_out;
  const size_t nXh = (size_t)N_ROWS * DIM * sizeof(_Float16);   // 64 MiB
  const size_t nCh = (size_t)K_CENT * DIM * sizeof(_Float16);   // 4 MiB
  const size_t nCsq = (size_t)K_CENT * sizeof(float);           // 16 KiB
  const size_t nBest = (size_t)N_ROWS * 8;                      // 512 KiB

  if (ws_size >= nXh + nCh + nCsq + nBest) {
    _Float16* xh = (_Float16*)d_ws;
    _Float16* ch = (_Float16*)((char*)d_ws + nXh);
    float* csqg = (float*)((char*)d_ws + nXh + nCh);
    unsigned long long* gbest = (unsigned long long*)((char*)d_ws + nXh + nCh + nCsq);
    const size_t total8 = ((size_t)N_ROWS + K_CENT) * DIM / 8;
    hipMemsetAsync(gbest, 0xFF, nBest, stream);
    prep_convert<<<(unsigned)((total8 + 255) / 256), 256, 0, stream>>>(x, cent, xh, ch, csqg);
    kmeans_argmin<2><<<1024, THREADS, 0, stream>>>(x, cent, xh, ch, csqg, gbest, out);
    finalize_out<<<N_ROWS / 256, 256, 0, stream>>>(gbest, out);
  } else {
    kmeans_argmin<0><<<512, THREADS, 0, stream>>>(x, cent, nullptr, nullptr, nullptr, nullptr, out);
  }
}

// Round 5
// 799.533 us; speedup vs baseline: 5.0519x; 5.0519x over previous
//
#include <hip/hip_runtime.h>

#define N_ROWS 65536
#define DIM    512
#define K_CENT 4096
#define TILE_M 128
#define TILE_N 128
#define BK     32
#define KSTEPS (DIM / BK)        // 16
#define NKT    (K_CENT / TILE_N) // 32 total kt tiles
#define NKT_SPLIT 16             // kt tiles per block in split mode
#define THREADS 256
#define MARGIN 6.0f
#define CAND_CAP 1536
#define COMPACT_TRIG 1024

typedef _Float16 half8 __attribute__((ext_vector_type(8)));
typedef float floatx4 __attribute__((ext_vector_type(4)));

// order-preserving float<->uint map
__device__ __forceinline__ unsigned mapF(float f) {
  unsigned u = __float_as_uint(f);
  return (u & 0x80000000u) ? ~u : (u | 0x80000000u);
}
__device__ __forceinline__ float unmapF(unsigned m) {
  unsigned u = (m & 0x80000000u) ? (m ^ 0x80000000u) : ~m;
  return __uint_as_float(u);
}

__device__ __forceinline__ void gload_lds16(const void* g, void* l) {
  __builtin_amdgcn_global_load_lds(
      (const __attribute__((address_space(1))) void*)g,
      (__attribute__((address_space(3))) void*)l, 16, 0, 0);
}

// fp32 -> fp16 conversion for x and center; csq (||c_fp16||^2) fused into the
// center branch (each 64-lane wave covers exactly one 512-dim center row).
__global__ void prep_convert(const float* __restrict__ x, const float* __restrict__ c,
                             _Float16* __restrict__ xh, _Float16* __restrict__ ch,
                             float* __restrict__ csqg) {
  const size_t nx = (size_t)N_ROWS * DIM;
  size_t i = ((size_t)blockIdx.x * blockDim.x + threadIdx.x) * 8;
  if (i < nx) {
    floatx4 a = *(const floatx4*)(x + i);
    floatx4 b = *(const floatx4*)(x + i + 4);
    half8 h;
#pragma unroll
    for (int e = 0; e < 4; ++e) { h[e] = (_Float16)a[e]; h[4 + e] = (_Float16)b[e]; }
    *(half8*)(xh + i) = h;
  } else if (i < nx + (size_t)K_CENT * DIM) {
    size_t off = i - nx;
    floatx4 a = *(const floatx4*)(c + off);
    floatx4 b = *(const floatx4*)(c + off + 4);
    half8 h;
    float s = 0.f;
#pragma unroll
    for (int e = 0; e < 4; ++e) { h[e] = (_Float16)a[e]; h[4 + e] = (_Float16)b[e]; }
#pragma unroll
    for (int e = 0; e < 8; ++e) { float v = (float)h[e]; s += v * v; }
    *(half8*)(ch + off) = h;
#pragma unroll
    for (int o = 1; o < 64; o <<= 1) s += __shfl_xor(s, o, 64);
    if ((threadIdx.x & 63) == 0) csqg[off >> 9] = s;
  }
}

__global__ void finalize_out(const unsigned long long* __restrict__ gbest,
                             int* __restrict__ out) {
  int i = blockIdx.x * blockDim.x + threadIdx.x;
  out[i] = (int)(gbest[i] & 0xFFFull);
}

// MODE 0: no ws fallback (fp32 loads, on-the-fly convert, LDS csq, all 32 kt,
//         local best, direct out write, grid 512)
// MODE 2: fp16+csq pre-computed in ws, SPLIT-K over centers: grid 1024,
//         block b handles rows (b&511)*128 and kt range ((b>>9)*16 .. +16);
//         results merged via global fp64-packed-key atomicMin in ws.
//
// 256 threads = 4 waves (2x2 wave grid), block tile 128x128, wave tile 64x64
// (16 MFMA / ks / wave), 16x16x32 f16 MFMA, BK=32. Reg budget: 64 AGPR acc +
// ~64 arch VGPR = 128/wave -> 4 waves/SIMD -> 4 blocks/CU (the point of this
// round: 4 independent barrier domains). NEVER request 8 waves/EU with this
// wave tile — R4 spilled the accumulators (8.9 GB scratch traffic).
// XOR chunk swizzle ((row>>1)&3) keeps ds_read_b128 conflict-free while
// staying compatible with global_load_lds lane-contiguous dst.
template <int MODE>
__global__ __launch_bounds__(THREADS, 4)
void kmeans_argmin(const float* __restrict__ x, const float* __restrict__ cent,
                   const _Float16* __restrict__ xh, const _Float16* __restrict__ ch,
                   const float* __restrict__ csqg, unsigned long long* __restrict__ gbest,
                   int* __restrict__ out) {
  __shared__ _Float16 ldsA[TILE_M * BK];        // 8 KB
  __shared__ _Float16 ldsB[TILE_N * BK];        // 8 KB
  __shared__ float csq4[TILE_N][4];             // 2 KB (MODE 0 only)
  __shared__ unsigned sminU[TILE_M];
  __shared__ unsigned long long best[TILE_M];   // MODE 0 only
  __shared__ unsigned candKey[CAND_CAP];        // 6 KB
  __shared__ float candS[CAND_CAP];             // 6 KB
  __shared__ int candCount;

  char* ldsAc = (char*)ldsA;
  char* ldsBc = (char*)ldsB;

  const int t = threadIdx.x;
  const int lane = t & 63;
  const int wave = t >> 6;   // 0..3
  const int wm = wave >> 1;  // 0..1 row-waves
  const int wn = wave & 1;   // 0..1 col-waves
  const int quad = lane >> 4;
  const int l15 = lane & 15;
  const int rowBlock = (MODE == 2) ? (blockIdx.x & 511) * TILE_M : blockIdx.x * TILE_M;
  const int ktStart = (MODE == 2) ? (int)(blockIdx.x >> 9) * NKT_SPLIT : 0;
  const int ktEnd = ktStart + ((MODE == 2) ? NKT_SPLIT : NKT);

  if (t < TILE_M) { sminU[t] = 0xFFFFFFFFu; if (MODE == 0) best[t] = ~0ull; }
  if (t == 0) candCount = 0;

  // staging: thread t owns slots t and t+256 in each tile (512 x 16B chunks).
  const int sr0 = t >> 2;
  const int sr1 = (t + 256) >> 2;
  const int sck0 = (t & 3) ^ ((sr0 >> 1) & 3);
  const int sck1 = (t & 3) ^ ((sr1 >> 1) & 3);

  for (int kt = ktStart; kt < ktEnd; ++kt) {
    const int ktBase = kt * TILE_N;
    if (MODE == 0) { ((float*)csq4)[t] = 0.f; ((float*)csq4)[t + 256] = 0.f; }
    floatx4 acc[4][4];
#pragma unroll
    for (int fm = 0; fm < 4; ++fm)
#pragma unroll
      for (int fn = 0; fn < 4; ++fn) acc[fm][fn] = (floatx4){0.f, 0.f, 0.f, 0.f};

    for (int ks = 0; ks < KSTEPS; ++ks) {
      const int kd = ks * BK;
      if (MODE == 2) {
        gload_lds16(xh + (size_t)(rowBlock + sr0) * DIM + kd + sck0 * 8,
                    ldsAc + (size_t)wave * 1024);
        gload_lds16(xh + (size_t)(rowBlock + sr1) * DIM + kd + sck1 * 8,
                    ldsAc + 4096 + (size_t)wave * 1024);
        gload_lds16(ch + (size_t)(ktBase + sr0) * DIM + kd + sck0 * 8,
                    ldsBc + (size_t)wave * 1024);
        gload_lds16(ch + (size_t)(ktBase + sr1) * DIM + kd + sck1 * 8,
                    ldsBc + 4096 + (size_t)wave * 1024);
      } else {
#pragma unroll
        for (int p = 0; p < 2; ++p) {
          int sr = p ? sr1 : sr0;
          int sck = p ? sck1 : sck0;
          int slot = p * 256 + t;
          const float* gA = x + (size_t)(rowBlock + sr) * DIM + kd + sck * 8;
          const float* gB = cent + (size_t)(ktBase + sr) * DIM + kd + sck * 8;
          floatx4 a0 = *(const floatx4*)gA, a1 = *(const floatx4*)(gA + 4);
          floatx4 b0 = *(const floatx4*)gB, b1 = *(const floatx4*)(gB + 4);
          half8 ha, hb;
          float s = 0.f;
#pragma unroll
          for (int e = 0; e < 4; ++e) {
            ha[e] = (_Float16)a0[e]; ha[4 + e] = (_Float16)a1[e];
            hb[e] = (_Float16)b0[e]; hb[4 + e] = (_Float16)b1[e];
          }
#pragma unroll
          for (int e = 0; e < 8; ++e) { float v = (float)hb[e]; s += v * v; }
          *(half8*)(ldsAc + (size_t)slot * 16) = ha;
          *(half8*)(ldsBc + (size_t)slot * 16) = hb;
          csq4[sr][slot & 3] += s;
        }
      }
      __syncthreads();

      half8 af[4], bf[4];
#pragma unroll
      for (int fm = 0; fm < 4; ++fm) {
        int row = wm * 64 + fm * 16 + l15;
        int slot = (row << 2) | (quad ^ ((row >> 1) & 3));
        af[fm] = *(const half8*)(ldsAc + slot * 16);
      }
#pragma unroll
      for (int fn = 0; fn < 4; ++fn) {
        int cl = wn * 64 + fn * 16 + l15;
        int slot = (cl << 2) | (quad ^ ((cl >> 1) & 3));
        bf[fn] = *(const half8*)(ldsBc + slot * 16);
      }
#pragma unroll
      for (int fm = 0; fm < 4; ++fm)
#pragma unroll
        for (int fn = 0; fn < 4; ++fn)
          acc[fm][fn] = __builtin_amdgcn_mfma_f32_16x16x32_f16(af[fm], bf[fn], acc[fm][fn], 0, 0, 0);
      __syncthreads();
    }

    // ---- epilogue: s = ||c||^2 - 2*cross (||x||^2 constant per row, dropped)
    // C layout 16x16: col = lane&15, row = quad*4 + e  [m89-verified]
    float cs[4];
#pragma unroll
    for (int fn = 0; fn < 4; ++fn) {
      int cl = wn * 64 + fn * 16 + l15;
      cs[fn] = (MODE == 2) ? csqg[ktBase + cl]
                           : (csq4[cl][0] + csq4[cl][1] + csq4[cl][2] + csq4[cl][3]);
    }

    // tighten running min FIRST (shfl pre-reduce over the 16 lanes sharing rows)
#pragma unroll
    for (int fm = 0; fm < 4; ++fm)
#pragma unroll
      for (int e = 0; e < 4; ++e) {
        float v = 3.4e38f;
#pragma unroll
        for (int fn = 0; fn < 4; ++fn)
          v = fminf(v, cs[fn] - 2.f * acc[fm][fn][e]);
        v = fminf(v, __shfl_xor(v, 1, 64));
        v = fminf(v, __shfl_xor(v, 2, 64));
        v = fminf(v, __shfl_xor(v, 4, 64));
        v = fminf(v, __shfl_xor(v, 8, 64));
        if (l15 == 0)
          atomicMin(&sminU[wm * 64 + fm * 16 + quad * 4 + e], mapF(v));
      }
    __syncthreads();

    float thrR[4][4];
#pragma unroll
    for (int fm = 0; fm < 4; ++fm)
#pragma unroll
      for (int e = 0; e < 4; ++e)
        thrR[fm][e] = unmapF(sminU[wm * 64 + fm * 16 + quad * 4 + e]) + MARGIN;

    // collect against the tightened (still prefix, hence superset) threshold
#pragma unroll
    for (int fn = 0; fn < 4; ++fn) {
      int k = ktBase + wn * 64 + fn * 16 + l15;
#pragma unroll
      for (int fm = 0; fm < 4; ++fm)
#pragma unroll
        for (int e = 0; e < 4; ++e) {
          float s = cs[fn] - 2.f * acc[fm][fn][e];
          if (s <= thrR[fm][e]) {
            int idx = atomicAdd(&candCount, 1);
            if (idx < CAND_CAP) {
              candKey[idx] = ((unsigned)k << 7) | (unsigned)(wm * 64 + fm * 16 + quad * 4 + e);
              candS[idx] = s;
            }
          }
        }
    }
    __syncthreads();

    // compaction backstop against tightened threshold (rarely triggers)
    if (candCount > COMPACT_TRIG) {
      int cc = candCount; if (cc > CAND_CAP) cc = CAND_CAP;
      unsigned myK[8]; float myS[8]; int myN = 0;
      for (int i = t; i < cc; i += THREADS) {
        int rl = candKey[i] & 127;
        if (candS[i] <= unmapF(sminU[rl]) + MARGIN && myN < 8) {
          myK[myN] = candKey[i]; myS[myN] = candS[i]; ++myN;
        }
      }
      __syncthreads();
      if (t == 0) candCount = 0;
      __syncthreads();
      int base = atomicAdd(&candCount, myN);
      for (int j = 0; j < myN; ++j) { candKey[base + j] = myK[j]; candS[base + j] = myS[j]; }
      __syncthreads();
    }
  }

  // ---- fp64-exact refinement of surviving candidates (original fp32 inputs)
  int cnt = candCount; if (cnt > CAND_CAP) cnt = CAND_CAP;
  const int g = t >> 4;   // 16 groups of 16 lanes
  const int sl = t & 15;
  for (int ci = g; ci < cnt; ci += 16) {
    unsigned cd = candKey[ci];
    int rl = cd & 127;
    if (candS[ci] > unmapF(sminU[rl]) + MARGIN) continue;  // group-uniform branch
    int k = cd >> 7;
    const float* xr = x + (size_t)(rowBlock + rl) * DIM;
    const float* cr = cent + (size_t)k * DIM;
    double d = 0.0;
#pragma unroll
    for (int j = 0; j < DIM / 64; ++j) {
      floatx4 xv = *(const floatx4*)(xr + j * 64 + sl * 4);
      floatx4 cv = *(const floatx4*)(cr + j * 64 + sl * 4);
#pragma unroll
      for (int e = 0; e < 4; ++e) {
        double df = (double)xv[e] - (double)cv[e];
        d += df * df;
      }
    }
#pragma unroll
    for (int off = 1; off < 16; off <<= 1) d += __shfl_xor(d, off, 64);
    if (sl == 0) {
      // positive doubles order as uint64; low 12 mantissa bits -> index (ties: lower k)
      unsigned long long key =
          ((unsigned long long)__double_as_longlong(d) & ~0xFFFull) | (unsigned long long)k;
      if (MODE == 2) atomicMin(&gbest[rowBlock + rl], key);
      else           atomicMin(&best[rl], key);
    }
  }
  if (MODE == 0) {
    __syncthreads();
    if (t < TILE_M) out[rowBlock + t] = (int)(best[t] & 0xFFFull);
  }
}

extern "C" void kernel_launch(void* const* d_in, const int* in_sizes, int n_in,
                              void* d_out, int out_size, void* d_ws, size_t ws_size,
                              hipStream_t stream) {
  const float* x = (const float*)d_in[0];
  const float* cent = (const float*)d_in[1];
  int* out = (int*)d_out;
  const size_t nXh = (size_t)N_ROWS * DIM * sizeof(_Float16);   // 64 MiB
  const size_t nCh = (size_t)K_CENT * DIM * sizeof(_Float16);   // 4 MiB
  const size_t nCsq = (size_t)K_CENT * sizeof(float);           // 16 KiB
  const size_t nBest = (size_t)N_ROWS * 8;                      // 512 KiB

  if (ws_size >= nXh + nCh + nCsq + nBest) {
    _Float16* xh = (_Float16*)d_ws;
    _Float16* ch = (_Float16*)((char*)d_ws + nXh);
    float* csqg = (float*)((char*)d_ws + nXh + nCh);
    unsigned long long* gbest = (unsigned long long*)((char*)d_ws + nXh + nCh + nCsq);
    const size_t total8 = ((size_t)N_ROWS + K_CENT) * DIM / 8;
    hipMemsetAsync(gbest, 0xFF, nBest, stream);
    prep_convert<<<(unsigned)((total8 + 255) / 256), 256, 0, stream>>>(x, cent, xh, ch, csqg);
    kmeans_argmin<2><<<1024, THREADS, 0, stream>>>(x, cent, xh, ch, csqg, gbest, out);
    finalize_out<<<N_ROWS / 256, 256, 0, stream>>>(gbest, out);
  } else {
    kmeans_argmin<0><<<512, THREADS, 0, stream>>>(x, cent, nullptr, nullptr, nullptr, nullptr, out);
  }
}